// Round 8
// baseline (237.813 us; speedup 1.0000x reference)
//
#include <hip/hip_runtime.h>

__device__ __forceinline__ void gload_lds16(const float* g, float* l) {
    __builtin_amdgcn_global_load_lds((const __attribute__((address_space(1))) void*)g,
                                     (__attribute__((address_space(3))) void*)l, 16, 0, 0);
}

// bf16 helpers (storage = unsigned short, layout identical to W)
__device__ __forceinline__ unsigned int f2bf1(float f) {
    union { float f; unsigned int u; } v; v.f = f;
    return (v.u + 0x7fffu + ((v.u >> 16) & 1u)) >> 16;   // RNE
}
__device__ __forceinline__ unsigned int packbf(float a, float b) {
    return f2bf1(a) | (f2bf1(b) << 16);
}
__device__ __forceinline__ float2 bf2x(unsigned int p) {
    union { unsigned int u; float f; } lo, hi;
    lo.u = p << 16; hi.u = p & 0xffff0000u;
    return make_float2(lo.f, hi.f);
}

// ---- transpose: x (B=64,I=8,C=2048) -> xt[c][i][b] ----
__global__ __launch_bounds__(256) void transpose_kernel(const float* __restrict__ x,
                                                        float* __restrict__ xt) {
    __shared__ float tile[64][65];
    const int bi0 = (blockIdx.x >> 5) << 6;    // bi = b*8+i
    const int c0  = (blockIdx.x & 31) << 6;
    const int tx = threadIdx.x & 63, ty = threadIdx.x >> 6;
#pragma unroll
    for (int p = 0; p < 16; ++p)
        tile[ty + p * 4][tx] = x[(size_t)(bi0 + ty + p * 4) * 2048 + c0 + tx];
    __syncthreads();
#pragma unroll
    for (int p = 0; p < 16; ++p) {
        int bi = bi0 + tx;
        xt[(size_t)(c0 + ty + p * 4) * 512 + (bi & 7) * 64 + (bi >> 3)] = tile[tx][ty + p * 4];
    }
}

// ---- s-pass: part[chunk][u][d][b] = sum_{c in chunk} cij[c,u]*sum_i W[c,u,d,i]*x[b,i,c]
// grid = 64 chunks(32c) x 32 u (u fast) = 2048 blocks; block 256 = 4 waves.
// Slab = 4 c (8 KB), double-buffered via global_load_lds; wave w stages AND
// computes c-local w of each slab. LDS 18.4 KB -> up to 8 blocks/CU.
// lane: dg = l>>4 (d-group), bq = l&15 (b-quad) -> acc[16].
// MODE: 0 = fp32 W, 1 = fp32 W + write bf16 copy, 2 = read bf16 W.
template <int UNIFORM, int MODE>
__global__ __launch_bounds__(256) void s_kernel8(const float* __restrict__ xt,
                                                 const float* __restrict__ W,
                                                 unsigned short* __restrict__ Wb,
                                                 const float* __restrict__ cij,
                                                 float* __restrict__ part) {
    const int chunk = blockIdx.x >> 5;    // 0..63
    const int u     = blockIdx.x & 31;
    const int t = threadIdx.x, w = t >> 6, l = t & 63;
    const int dg = l >> 4, bq = l & 15;

    __shared__ float lds[4608];           // [0,4096): 2 x 2048 stage bufs; red reuse [0,4352)

    const int cbase = chunk * 32;
    float acc[16];
#pragma unroll
    for (int j = 0; j < 16; ++j) acc[j] = 0.f;

    // prologue: stage slab 0 (wave-uniform LDS dest, per-lane global src)
    {
        const float* g = xt + (size_t)(cbase + w) * 512 + l * 4;
        gload_lds16(g,       lds + w * 512);
        gload_lds16(g + 256, lds + w * 512 + 256);
    }
    __syncthreads();

#pragma unroll 1
    for (int sl = 0; sl < 8; ++sl) {
        const int cur = (sl & 1) * 2048;
        if (sl < 7) {
            const int nxt = ((sl + 1) & 1) * 2048;
            const float* g = xt + (size_t)(cbase + (sl + 1) * 4 + w) * 512 + l * 4;
            gload_lds16(g,       lds + nxt + w * 512);
            gload_lds16(g + 256, lds + nxt + w * 512 + 256);
        }
        const int c = cbase + sl * 4 + w;
        const float cw = UNIFORM ? 0.03125f : cij[c * 32 + u];
        const size_t wbase = ((size_t)c * 32 + u) * 128 + dg * 32;
        float4 wv[8];
        if (MODE == 2) {
            const uint4* Wp = reinterpret_cast<const uint4*>(Wb + wbase);
            unsigned int wu[16];
#pragma unroll
            for (int q = 0; q < 4; ++q) {
                uint4 h = Wp[q];
                wu[q * 4 + 0] = h.x; wu[q * 4 + 1] = h.y;
                wu[q * 4 + 2] = h.z; wu[q * 4 + 3] = h.w;
            }
#pragma unroll
            for (int k = 0; k < 8; ++k) {
                float2 a = bf2x(wu[2 * k]), b = bf2x(wu[2 * k + 1]);
                wv[k] = make_float4(a.x, a.y, b.x, b.y);
            }
        } else {
            const float4* Wp = reinterpret_cast<const float4*>(W + wbase);
#pragma unroll
            for (int q = 0; q < 8; ++q) wv[q] = Wp[q];
            if (MODE == 1 && bq == 0) {
                uint4* dst = reinterpret_cast<uint4*>(Wb + wbase);
#pragma unroll
                for (int q = 0; q < 4; ++q) {
                    uint4 o;
                    o.x = packbf(wv[2 * q].x,     wv[2 * q].y);
                    o.y = packbf(wv[2 * q].z,     wv[2 * q].w);
                    o.z = packbf(wv[2 * q + 1].x, wv[2 * q + 1].y);
                    o.w = packbf(wv[2 * q + 1].z, wv[2 * q + 1].w);
                    dst[q] = o;
                }
            }
        }
        float4 xv[8];
#pragma unroll
        for (int q = 0; q < 8; ++q)
            xv[q] = *reinterpret_cast<const float4*>(lds + cur + w * 512 + q * 64 + bq * 4);
#pragma unroll
        for (int dd = 0; dd < 4; ++dd) {
            const float4 wa = wv[dd * 2], wb = wv[dd * 2 + 1];
            float uh0 = wa.x * xv[0].x + wa.y * xv[1].x + wa.z * xv[2].x + wa.w * xv[3].x
                      + wb.x * xv[4].x + wb.y * xv[5].x + wb.z * xv[6].x + wb.w * xv[7].x;
            float uh1 = wa.x * xv[0].y + wa.y * xv[1].y + wa.z * xv[2].y + wa.w * xv[3].y
                      + wb.x * xv[4].y + wb.y * xv[5].y + wb.z * xv[6].y + wb.w * xv[7].y;
            float uh2 = wa.x * xv[0].z + wa.y * xv[1].z + wa.z * xv[2].z + wa.w * xv[3].z
                      + wb.x * xv[4].z + wb.y * xv[5].z + wb.z * xv[6].z + wb.w * xv[7].z;
            float uh3 = wa.x * xv[0].w + wa.y * xv[1].w + wa.z * xv[2].w + wa.w * xv[3].w
                      + wb.x * xv[4].w + wb.y * xv[5].w + wb.z * xv[6].w + wb.w * xv[7].w;
            acc[dd * 4 + 0] += cw * uh0;
            acc[dd * 4 + 1] += cw * uh1;
            acc[dd * 4 + 2] += cw * uh2;
            acc[dd * 4 + 3] += cw * uh3;
        }
        __syncthreads();
    }

    // cross-wave reduce: reuse lds (stride 17, conflict-free)
#pragma unroll
    for (int j = 0; j < 16; ++j) lds[(w * 64 + l) * 17 + j] = acc[j];
    __syncthreads();
    const int l2 = t & 63, k = t >> 6;
    const int dg2 = l2 >> 4, bq2 = l2 & 15;
    float4 o;
    float* op = &o.x;
#pragma unroll
    for (int bb = 0; bb < 4; ++bb)
        op[bb] = lds[(0 * 64 + l2) * 17 + k * 4 + bb] + lds[(1 * 64 + l2) * 17 + k * 4 + bb]
               + lds[(2 * 64 + l2) * 17 + k * 4 + bb] + lds[(3 * 64 + l2) * 17 + k * 4 + bb];
    *reinterpret_cast<float4*>(part + (((size_t)chunk * 32 + u) * 16 + dg2 * 4 + k) * 64 + bq2 * 4) = o;
}

// ---- s[u][d][b] = sum over 64 chunks ----
__global__ __launch_bounds__(256) void reduce_kernel(const float4* __restrict__ part4,
                                                     float4* __restrict__ s4) {
    int n = blockIdx.x * 256 + threadIdx.x;     // grid = 32 -> 8192 float4
    float4 a = part4[n];
#pragma unroll
    for (int k = 1; k < 64; ++k) {
        float4 b = part4[(size_t)k * 8192 + n];
        a.x += b.x; a.y += b.y; a.z += b.z; a.w += b.w;
    }
    s4[n] = a;
}

// ---- squash (reference quirk: mag over U per (b,d)); s layout [u][d][b] ----
__global__ __launch_bounds__(256) void v_kernel2(const float* __restrict__ s,
                                                 float* __restrict__ v,
                                                 float* __restrict__ out) {
    int n = blockIdx.x * 256 + threadIdx.x;     // grid = 4 -> 1024 = B*D
    int b = n >> 4, d = n & 15;
    float sv[32];
    float msq = 0.f;
#pragma unroll
    for (int u = 0; u < 32; ++u) {
        sv[u] = s[(u * 16 + d) * 64 + b];
        msq += sv[u] * sv[u];
    }
    float scale = msq / ((1.f + msq) * sqrtf(msq));
#pragma unroll
    for (int u = 0; u < 32; ++u) {
        float val = sv[u] * scale;
        v[(b * 32 + u) * 16 + d] = val;
        out[(b * 32 + u) * 16 + d] = val;
    }
}

// ---- delta + fused softmax: 1 c per block, grid = 2048 ----
// lane: u = t>>3, d-pair = (t&7)*2
template <int FIRST, int WBF16>
__global__ __launch_bounds__(256) void delta_kernel8(const float* __restrict__ xt,
                                                     const float* __restrict__ W,
                                                     const unsigned short* __restrict__ Wb,
                                                     const float* __restrict__ v,
                                                     float* __restrict__ bij,
                                                     float* __restrict__ cij) {
    const int c = blockIdx.x;
    const int t = threadIdx.x;
    __shared__ float xs[512];                   // [b][i]
    __shared__ float sm[32];
    {
        // xt row is [i*64+b]; scatter to xs[b*8+i]
        const float2 vq = reinterpret_cast<const float2*>(xt + (size_t)c * 512)[t];
        int e0 = t * 2, e1 = t * 2 + 1;
        xs[(e0 & 63) * 8 + (e0 >> 6)] = vq.x;
        xs[(e1 & 63) * 8 + (e1 >> 6)] = vq.y;
    }
    __syncthreads();
    const int u = t >> 3, d0 = (t & 7) * 2;
    float4 a00, a01, a10, a11;
    if (WBF16) {
        const uint4* W0 = reinterpret_cast<const uint4*>(Wb + ((size_t)c * 32 + u) * 128 + d0 * 8);
        uint4 h0 = W0[0], h1 = W0[1];
        float2 p;
        p = bf2x(h0.x); a00.x = p.x; a00.y = p.y;  p = bf2x(h0.y); a00.z = p.x; a00.w = p.y;
        p = bf2x(h0.z); a01.x = p.x; a01.y = p.y;  p = bf2x(h0.w); a01.z = p.x; a01.w = p.y;
        p = bf2x(h1.x); a10.x = p.x; a10.y = p.y;  p = bf2x(h1.y); a10.z = p.x; a10.w = p.y;
        p = bf2x(h1.z); a11.x = p.x; a11.y = p.y;  p = bf2x(h1.w); a11.z = p.x; a11.w = p.y;
    } else {
        const float4* W0 = reinterpret_cast<const float4*>(W + ((size_t)c * 32 + u) * 128 + d0 * 8);
        a00 = W0[0]; a01 = W0[1]; a10 = W0[2]; a11 = W0[3];
    }
    float p0 = 0.f, p1 = 0.f;
#pragma unroll 4
    for (int b = 0; b < 64; b += 2) {
        {
            const float2 vv = *reinterpret_cast<const float2*>(v + (b * 32 + u) * 16 + d0);
            const float4 xa = *reinterpret_cast<const float4*>(xs + b * 8);
            const float4 xb = *reinterpret_cast<const float4*>(xs + b * 8 + 4);
            float uh0 = a00.x * xa.x + a00.y * xa.y + a00.z * xa.z + a00.w * xa.w
                      + a01.x * xb.x + a01.y * xb.y + a01.z * xb.z + a01.w * xb.w;
            float uh1 = a10.x * xa.x + a10.y * xa.y + a10.z * xa.z + a10.w * xa.w
                      + a11.x * xb.x + a11.y * xb.y + a11.z * xb.z + a11.w * xb.w;
            p0 += uh0 * vv.x + uh1 * vv.y;
        }
        {
            const float2 vv = *reinterpret_cast<const float2*>(v + ((b + 1) * 32 + u) * 16 + d0);
            const float4 xa = *reinterpret_cast<const float4*>(xs + (b + 1) * 8);
            const float4 xb = *reinterpret_cast<const float4*>(xs + (b + 1) * 8 + 4);
            float uh0 = a00.x * xa.x + a00.y * xa.y + a00.z * xa.z + a00.w * xa.w
                      + a01.x * xb.x + a01.y * xb.y + a01.z * xb.z + a01.w * xb.w;
            float uh1 = a10.x * xa.x + a10.y * xa.y + a10.z * xa.z + a10.w * xa.w
                      + a11.x * xb.x + a11.y * xb.y + a11.z * xb.z + a11.w * xb.w;
            p1 += uh0 * vv.x + uh1 * vv.y;
        }
    }
    float partial = p0 + p1;
    partial += __shfl_xor(partial, 1);
    partial += __shfl_xor(partial, 2);
    partial += __shfl_xor(partial, 4);
    if ((t & 7) == 0) {
        float r = partial * (1.0f / 64.0f);
        if (!FIRST) r += bij[c * 32 + u];
        bij[c * 32 + u] = r;
        sm[u] = r;
    }
    __syncthreads();
    if (t < 32) {                                // lanes 0..31 of wave 0
        float val = sm[t];
        float m = val;
#pragma unroll
        for (int mask = 16; mask >= 1; mask >>= 1) m = fmaxf(m, __shfl_xor(m, mask));
        float e = expf(val - m);
        float ssum = e;
#pragma unroll
        for (int mask = 16; mask >= 1; mask >>= 1) ssum += __shfl_xor(ssum, mask);
        cij[c * 32 + t] = e / ssum;
    }
}

extern "C" void kernel_launch(void* const* d_in, const int* in_sizes, int n_in,
                              void* d_out, int out_size, void* d_ws, size_t ws_size,
                              hipStream_t stream) {
    const float* x = (const float*)d_in[0];   // (B, I, C) = (64, 8, 2048)
    const float* W = (const float*)d_in[1];   // (C, U, D, I) = (2048, 32, 16, 8)
    float* out = (float*)d_out;

    float* ws   = (float*)d_ws;
    float* xt   = ws;                   // 1,048,576 floats [c][i][b]
    float* bij  = xt + 1048576;         // 65,536
    float* cij  = bij + 65536;          // 65,536
    float* s    = cij + 65536;          // 32,768
    float* v    = s + 32768;            // 32,768
    float* part = v + 32768;            // 64*U*D*B = 2,097,152
    unsigned short* Wb = (unsigned short*)(part + 2097152);   // 33,554,432 ushorts

    // floats before Wb: 3,342,336 (= 13,369,344 B) ; Wb = 67,108,864 B
    const bool BF = ws_size >= (size_t)3342336 * 4 + (size_t)33554432 * 2;

    transpose_kernel<<<256, 256, 0, stream>>>(x, xt);

    if (BF) {
        // it 0: uniform cij; s-pass also emits bf16 W copy
        s_kernel8<1, 1><<<2048, 256, 0, stream>>>(xt, W, Wb, cij, part);
        reduce_kernel<<<32, 256, 0, stream>>>((const float4*)part, (float4*)s);
        v_kernel2<<<4, 256, 0, stream>>>(s, v, out);
        delta_kernel8<1, 1><<<2048, 256, 0, stream>>>(xt, W, Wb, v, bij, cij);

        s_kernel8<0, 2><<<2048, 256, 0, stream>>>(xt, W, Wb, cij, part);
        reduce_kernel<<<32, 256, 0, stream>>>((const float4*)part, (float4*)s);
        v_kernel2<<<4, 256, 0, stream>>>(s, v, out);
        delta_kernel8<0, 1><<<2048, 256, 0, stream>>>(xt, W, Wb, v, bij, cij);

        s_kernel8<0, 2><<<2048, 256, 0, stream>>>(xt, W, Wb, cij, part);
        reduce_kernel<<<32, 256, 0, stream>>>((const float4*)part, (float4*)s);
        v_kernel2<<<4, 256, 0, stream>>>(s, v, out);
    } else {
        // fp32 fallback
        s_kernel8<1, 0><<<2048, 256, 0, stream>>>(xt, W, Wb, cij, part);
        reduce_kernel<<<32, 256, 0, stream>>>((const float4*)part, (float4*)s);
        v_kernel2<<<4, 256, 0, stream>>>(s, v, out);
        delta_kernel8<1, 0><<<2048, 256, 0, stream>>>(xt, W, Wb, v, bij, cij);

        s_kernel8<0, 0><<<2048, 256, 0, stream>>>(xt, W, Wb, cij, part);
        reduce_kernel<<<32, 256, 0, stream>>>((const float4*)part, (float4*)s);
        v_kernel2<<<4, 256, 0, stream>>>(s, v, out);
        delta_kernel8<0, 0><<<2048, 256, 0, stream>>>(xt, W, Wb, v, bij, cij);

        s_kernel8<0, 0><<<2048, 256, 0, stream>>>(xt, W, Wb, cij, part);
        reduce_kernel<<<32, 256, 0, stream>>>((const float4*)part, (float4*)s);
        v_kernel2<<<4, 256, 0, stream>>>(s, v, out);
    }
}

// Round 9
// 195.411 us; speedup vs baseline: 1.2170x; 1.2170x over previous
//
#include <hip/hip_runtime.h>

typedef __attribute__((ext_vector_type(8))) short short8;
typedef __attribute__((ext_vector_type(4))) float f32x4;

// bf16 helpers (RNE pack; storage layout identical to W)
__device__ __forceinline__ unsigned int f2bf1(float f) {
    union { float f; unsigned int u; } v; v.f = f;
    return (v.u + 0x7fffu + ((v.u >> 16) & 1u)) >> 16;
}
__device__ __forceinline__ unsigned int packbf(float a, float b) {
    return f2bf1(a) | (f2bf1(b) << 16);
}
__device__ __forceinline__ float2 bf2x(unsigned int p) {
    union { unsigned int u; float f; } lo, hi;
    lo.u = p << 16; hi.u = p & 0xffff0000u;
    return make_float2(lo.f, hi.f);
}

// ---- transpose: x (bi=512, c=2048) -> xt[c][bi]  (bi = b*8+i, so xt = [c][b][i]) ----
__global__ __launch_bounds__(256) void transpose_kernel(const float* __restrict__ x,
                                                        float* __restrict__ xt) {
    __shared__ float tile[64][65];
    const int bi0 = (blockIdx.x >> 5) << 6;    // 8 bi-tiles
    const int c0  = (blockIdx.x & 31) << 6;    // 32 c-tiles
    const int tx = threadIdx.x & 63, ty = threadIdx.x >> 6;
#pragma unroll
    for (int p = 0; p < 16; ++p)
        tile[ty + p * 4][tx] = x[(size_t)(bi0 + ty + p * 4) * 2048 + c0 + tx];
    __syncthreads();
#pragma unroll
    for (int p = 0; p < 16; ++p)
        xt[(size_t)(c0 + ty + p * 4) * 512 + bi0 + tx] = tile[tx][ty + p * 4];
}

// ---- one-time W (fp32) -> Wb (bf16), same element order ----
__global__ __launch_bounds__(256) void wconv_kernel(const float4* __restrict__ W4,
                                                    uint2* __restrict__ Wb2) {
    int n = blockIdx.x * 256 + threadIdx.x;     // grid 2048 -> 524288 threads
#pragma unroll
    for (int k = 0; k < 4; ++k) {
        int idx = n + k * 524288;               // 2,097,152 float4 total
        float4 wv = W4[idx];
        Wb2[idx] = make_uint2(packbf(wv.x, wv.y), packbf(wv.z, wv.w));
    }
}

// ---- MFMA s-pass ----
// part[bid][w][lane][r] where bid = chunk*32+u; thread holds D[d=(l>>4)*4+r][b=w*16+(l&15)]
// per quad q: c = chunk*32 + q*4 + (l>>4)
//   A-frag (m=l&15=d, k=(c-local)*8+i): Wb[(c*32+u)*128 + (l&15)*8 .. +8]   (16B contig)
//   B-frag (n=l&15 -> b=w*16+n, same k): cij[c,u] * xt[c*512 + b*8 .. +8]    (pack to bf16)
template <int UNIFORM>
__global__ __launch_bounds__(256) void smfma_kernel(const float* __restrict__ xt,
                                                    const unsigned short* __restrict__ Wb,
                                                    const float* __restrict__ cij,
                                                    float* __restrict__ part) {
    const int chunk = blockIdx.x >> 5;          // 0..63 (32 c each)
    const int u     = blockIdx.x & 31;
    const int t = threadIdx.x, w = t >> 6, l = t & 63;
    const int m  = l & 15;
    const int kb = l >> 4;
    const int b  = w * 16 + m;

    f32x4 acc = {0.f, 0.f, 0.f, 0.f};
    const int c00 = chunk * 32;

#pragma unroll 4
    for (int q = 0; q < 8; ++q) {
        const int c = c00 + q * 4 + kb;
        uint4 av = *reinterpret_cast<const uint4*>(Wb + ((size_t)c * 32 + u) * 128 + m * 8);
        const float4* xp = reinterpret_cast<const float4*>(xt + ((size_t)c * 64 + b) * 8);
        float4 x0 = xp[0], x1 = xp[1];
        const float cw = UNIFORM ? 0.03125f : cij[c * 32 + u];
        uint4 bv;
        bv.x = packbf(x0.x * cw, x0.y * cw);
        bv.y = packbf(x0.z * cw, x0.w * cw);
        bv.z = packbf(x1.x * cw, x1.y * cw);
        bv.w = packbf(x1.z * cw, x1.w * cw);
        acc = __builtin_amdgcn_mfma_f32_16x16x32_bf16(
            __builtin_bit_cast(short8, av), __builtin_bit_cast(short8, bv), acc, 0, 0, 0);
    }

    *reinterpret_cast<f32x4*>(part + (size_t)blockIdx.x * 1024 + t * 4) = acc;
}

// ---- reduce over 64 chunks; emit s[u][d][b] ----
// thread = (u, w, lane); reads float4 part[(k*32+u)*1024 + w*256 + lane*4]
__global__ __launch_bounds__(256) void reduce_kernel(const float* __restrict__ part,
                                                     float* __restrict__ s) {
    const int tid = blockIdx.x * 256 + threadIdx.x;   // grid 32 -> 8192
    const int u = tid >> 8, w = (tid >> 6) & 3, lane = tid & 63;
    const float4* p = reinterpret_cast<const float4*>(part) + ((size_t)u * 256 + w * 64 + lane);
    float4 a = p[0];
#pragma unroll
    for (int k = 1; k < 64; ++k) {
        float4 q = p[(size_t)k * 8192];
        a.x += q.x; a.y += q.y; a.z += q.z; a.w += q.w;
    }
    const float* ap = &a.x;
    const int bcol = w * 16 + (lane & 15);
#pragma unroll
    for (int r = 0; r < 4; ++r) {
        const int d = (lane >> 4) * 4 + r;
        s[((size_t)u * 16 + d) * 64 + bcol] = ap[r];
    }
}

// ---- squash (reference quirk: mag over U per (b,d)); s layout [u][d][b] ----
__global__ __launch_bounds__(256) void v_kernel2(const float* __restrict__ s,
                                                 float* __restrict__ v,
                                                 float* __restrict__ out) {
    int n = blockIdx.x * 256 + threadIdx.x;     // grid = 4 -> 1024 = B*D
    int b = n >> 4, d = n & 15;
    float sv[32];
    float msq = 0.f;
#pragma unroll
    for (int u = 0; u < 32; ++u) {
        sv[u] = s[(u * 16 + d) * 64 + b];
        msq += sv[u] * sv[u];
    }
    float scale = msq / ((1.f + msq) * sqrtf(msq));
#pragma unroll
    for (int u = 0; u < 32; ++u) {
        float val = sv[u] * scale;
        v[(b * 32 + u) * 16 + d] = val;
        out[(b * 32 + u) * 16 + d] = val;
    }
}

// ---- delta + fused softmax: 1 c per block, grid = 2048; bf16 W ----
// lane: u = t>>3, d-pair = (t&7)*2
template <int FIRST>
__global__ __launch_bounds__(256) void delta_kernel9(const float* __restrict__ xt,
                                                     const unsigned short* __restrict__ Wb,
                                                     const float* __restrict__ v,
                                                     float* __restrict__ bij,
                                                     float* __restrict__ cij) {
    const int c = blockIdx.x;
    const int t = threadIdx.x;
    __shared__ float xs[512];                   // xt row already [b][i]
    __shared__ float sm[32];
    xs[t]       = xt[(size_t)c * 512 + t];
    xs[t + 256] = xt[(size_t)c * 512 + t + 256];
    __syncthreads();

    const int u = t >> 3, d0 = (t & 7) * 2;
    float4 a00, a01, a10, a11;
    {
        const uint4* W0 = reinterpret_cast<const uint4*>(Wb + ((size_t)c * 32 + u) * 128 + d0 * 8);
        uint4 h0 = W0[0], h1 = W0[1];
        float2 p;
        p = bf2x(h0.x); a00.x = p.x; a00.y = p.y;  p = bf2x(h0.y); a00.z = p.x; a00.w = p.y;
        p = bf2x(h0.z); a01.x = p.x; a01.y = p.y;  p = bf2x(h0.w); a01.z = p.x; a01.w = p.y;
        p = bf2x(h1.x); a10.x = p.x; a10.y = p.y;  p = bf2x(h1.y); a10.z = p.x; a10.w = p.y;
        p = bf2x(h1.z); a11.x = p.x; a11.y = p.y;  p = bf2x(h1.w); a11.z = p.x; a11.w = p.y;
    }
    float p0 = 0.f, p1 = 0.f;
#pragma unroll 4
    for (int b = 0; b < 64; b += 2) {
        {
            const float2 vv = *reinterpret_cast<const float2*>(v + (b * 32 + u) * 16 + d0);
            const float4 xa = *reinterpret_cast<const float4*>(xs + b * 8);
            const float4 xb = *reinterpret_cast<const float4*>(xs + b * 8 + 4);
            float uh0 = a00.x * xa.x + a00.y * xa.y + a00.z * xa.z + a00.w * xa.w
                      + a01.x * xb.x + a01.y * xb.y + a01.z * xb.z + a01.w * xb.w;
            float uh1 = a10.x * xa.x + a10.y * xa.y + a10.z * xa.z + a10.w * xa.w
                      + a11.x * xb.x + a11.y * xb.y + a11.z * xb.z + a11.w * xb.w;
            p0 += uh0 * vv.x + uh1 * vv.y;
        }
        {
            const float2 vv = *reinterpret_cast<const float2*>(v + ((b + 1) * 32 + u) * 16 + d0);
            const float4 xa = *reinterpret_cast<const float4*>(xs + (b + 1) * 8);
            const float4 xb = *reinterpret_cast<const float4*>(xs + (b + 1) * 8 + 4);
            float uh0 = a00.x * xa.x + a00.y * xa.y + a00.z * xa.z + a00.w * xa.w
                      + a01.x * xb.x + a01.y * xb.y + a01.z * xb.z + a01.w * xb.w;
            float uh1 = a10.x * xa.x + a10.y * xa.y + a10.z * xa.z + a10.w * xa.w
                      + a11.x * xb.x + a11.y * xb.y + a11.z * xb.z + a11.w * xb.w;
            p1 += uh0 * vv.x + uh1 * vv.y;
        }
    }
    float partial = p0 + p1;
    partial += __shfl_xor(partial, 1);
    partial += __shfl_xor(partial, 2);
    partial += __shfl_xor(partial, 4);
    if ((t & 7) == 0) {
        float r = partial * (1.0f / 64.0f);
        if (!FIRST) r += bij[c * 32 + u];
        bij[c * 32 + u] = r;
        sm[u] = r;
    }
    __syncthreads();
    if (t < 32) {                                // lanes 0..31 of wave 0: softmax over u
        float val = sm[t];
        float m = val;
#pragma unroll
        for (int mask = 16; mask >= 1; mask >>= 1) m = fmaxf(m, __shfl_xor(m, mask));
        float e = expf(val - m);
        float ssum = e;
#pragma unroll
        for (int mask = 16; mask >= 1; mask >>= 1) ssum += __shfl_xor(ssum, mask);
        cij[c * 32 + t] = e / ssum;
    }
}

extern "C" void kernel_launch(void* const* d_in, const int* in_sizes, int n_in,
                              void* d_out, int out_size, void* d_ws, size_t ws_size,
                              hipStream_t stream) {
    const float* x = (const float*)d_in[0];   // (B, I, C) = (64, 8, 2048)
    const float* W = (const float*)d_in[1];   // (C, U, D, I) = (2048, 32, 16, 8) = 8.4M fp32
    float* out = (float*)d_out;

    float* ws   = (float*)d_ws;
    float* xt   = ws;                   // 1,048,576 floats [c][b][i]
    float* bij  = xt + 1048576;         // 65,536
    float* cij  = bij + 65536;          // 65,536
    float* s    = cij + 65536;          // 32,768
    float* v    = s + 32768;            // 32,768
    float* part = v + 32768;            // 2048 blocks * 1024 = 2,097,152
    unsigned short* Wb = (unsigned short*)(part + 2097152);   // 8,388,608 ushorts (16.8 MB)

    transpose_kernel<<<256, 256, 0, stream>>>(x, xt);
    wconv_kernel<<<2048, 256, 0, stream>>>((const float4*)W, (uint2*)Wb);

    // it 0: uniform cij (bij = 0)
    smfma_kernel<1><<<2048, 256, 0, stream>>>(xt, Wb, cij, part);
    reduce_kernel<<<32, 256, 0, stream>>>(part, s);
    v_kernel2<<<4, 256, 0, stream>>>(s, v, out);
    delta_kernel9<1><<<2048, 256, 0, stream>>>(xt, Wb, v, bij, cij);

    // it 1
    smfma_kernel<0><<<2048, 256, 0, stream>>>(xt, Wb, cij, part);
    reduce_kernel<<<32, 256, 0, stream>>>(part, s);
    v_kernel2<<<4, 256, 0, stream>>>(s, v, out);
    delta_kernel9<0><<<2048, 256, 0, stream>>>(xt, Wb, v, bij, cij);

    // it 2
    smfma_kernel<0><<<2048, 256, 0, stream>>>(xt, Wb, cij, part);
    reduce_kernel<<<32, 256, 0, stream>>>(part, s);
    v_kernel2<<<4, 256, 0, stream>>>(s, v, out);
}

// Round 10
// 194.379 us; speedup vs baseline: 1.2234x; 1.0053x over previous
//
#include <hip/hip_runtime.h>

typedef __attribute__((ext_vector_type(8))) short short8;
typedef __attribute__((ext_vector_type(4))) float f32x4;

__device__ __forceinline__ unsigned int f2bf1(float f) {
    union { float f; unsigned int u; } v; v.f = f;
    return (v.u + 0x7fffu + ((v.u >> 16) & 1u)) >> 16;   // RNE
}
__device__ __forceinline__ unsigned int packbf(float a, float b) {
    return f2bf1(a) | (f2bf1(b) << 16);
}
__device__ __forceinline__ float bf1(unsigned short h) {
    union { unsigned int u; float f; } v; v.u = ((unsigned int)h) << 16;
    return v.f;
}

// ---- transpose: x (bi=512, c=2048) -> xt[c][b][i] fp32  AND  x2b[c][i][b] bf16 ----
__global__ __launch_bounds__(256) void transpose_kernel(const float* __restrict__ x,
                                                        float* __restrict__ xt,
                                                        unsigned short* __restrict__ x2b) {
    __shared__ float tile[64][65];
    const int bi0 = (blockIdx.x >> 5) << 6;
    const int c0  = (blockIdx.x & 31) << 6;
    const int tx = threadIdx.x & 63, ty = threadIdx.x >> 6;
#pragma unroll
    for (int p = 0; p < 16; ++p)
        tile[ty + p * 4][tx] = x[(size_t)(bi0 + ty + p * 4) * 2048 + c0 + tx];
    __syncthreads();
#pragma unroll
    for (int p = 0; p < 16; ++p) {
        const int c = c0 + ty + p * 4;
        const int bi = bi0 + tx;
        const float val = tile[tx][ty + p * 4];
        xt[(size_t)c * 512 + bi] = val;                                    // [c][b][i]
        x2b[(size_t)c * 512 + (bi & 7) * 64 + (bi >> 3)] = (unsigned short)f2bf1(val); // [c][i][b]
    }
}

// ---- softmax over u per c ----
__global__ __launch_bounds__(256) void softmax_kernel(const float* __restrict__ bij,
                                                      float* __restrict__ cij) {
    int c = blockIdx.x * 256 + threadIdx.x;     // grid = 8
    float vals[32];
    float m = -1e30f;
#pragma unroll
    for (int u = 0; u < 32; ++u) { vals[u] = bij[c * 32 + u]; m = fmaxf(m, vals[u]); }
    float ssum = 0.f;
#pragma unroll
    for (int u = 0; u < 32; ++u) { vals[u] = expf(vals[u] - m); ssum += vals[u]; }
    float inv = 1.f / ssum;
#pragma unroll
    for (int u = 0; u < 32; ++u) cij[c * 32 + u] = vals[u] * inv;
}

// ---- MFMA s-pass (R9 structure). MODE 1: read W fp32 + write Wb; MODE 2: read Wb ----
template <int UNIFORM, int MODE>
__global__ __launch_bounds__(256) void smfma_kernel(const float* __restrict__ xt,
                                                    const float* __restrict__ W,
                                                    unsigned short* __restrict__ Wb,
                                                    const float* __restrict__ cij,
                                                    float* __restrict__ part) {
    const int chunk = blockIdx.x >> 5;          // 0..63 (32 c each)
    const int u     = blockIdx.x & 31;
    const int t = threadIdx.x, w = t >> 6, l = t & 63;
    const int m  = l & 15;
    const int kb = l >> 4;
    const int b  = w * 16 + m;

    f32x4 acc = {0.f, 0.f, 0.f, 0.f};
    const int c00 = chunk * 32;

#pragma unroll 4
    for (int q = 0; q < 8; ++q) {
        const int c = c00 + q * 4 + kb;
        const size_t wofs = ((size_t)c * 32 + u) * 128 + m * 8;
        uint4 av;
        if (MODE == 1) {
            const float4* Wp = reinterpret_cast<const float4*>(W + wofs);
            float4 w0 = Wp[0], w1 = Wp[1];
            av.x = packbf(w0.x, w0.y); av.y = packbf(w0.z, w0.w);
            av.z = packbf(w1.x, w1.y); av.w = packbf(w1.z, w1.w);
            if (w == 0) *reinterpret_cast<uint4*>(Wb + wofs) = av;
        } else {
            av = *reinterpret_cast<const uint4*>(Wb + wofs);
        }
        const float4* xp = reinterpret_cast<const float4*>(xt + ((size_t)c * 64 + b) * 8);
        float4 x0 = xp[0], x1 = xp[1];
        const float cw = UNIFORM ? 0.03125f : cij[c * 32 + u];
        uint4 bv;
        bv.x = packbf(x0.x * cw, x0.y * cw);
        bv.y = packbf(x0.z * cw, x0.w * cw);
        bv.z = packbf(x1.x * cw, x1.y * cw);
        bv.w = packbf(x1.z * cw, x1.w * cw);
        acc = __builtin_amdgcn_mfma_f32_16x16x32_bf16(
            __builtin_bit_cast(short8, av), __builtin_bit_cast(short8, bv), acc, 0, 0, 0);
    }

    *reinterpret_cast<f32x4*>(part + (size_t)blockIdx.x * 1024 + t * 4) = acc;
}

// ---- reduce over 64 chunks; emit s[u][d][b] ----
__global__ __launch_bounds__(256) void reduce_kernel(const float* __restrict__ part,
                                                     float* __restrict__ s) {
    const int tid = blockIdx.x * 256 + threadIdx.x;   // grid 32 -> 8192
    const int u = tid >> 8, w = (tid >> 6) & 3, lane = tid & 63;
    const float4* p = reinterpret_cast<const float4*>(part) + ((size_t)u * 256 + w * 64 + lane);
    float4 a = p[0];
#pragma unroll
    for (int k = 1; k < 64; ++k) {
        float4 q = p[(size_t)k * 8192];
        a.x += q.x; a.y += q.y; a.z += q.z; a.w += q.w;
    }
    const float* ap = &a.x;
    const int bcol = w * 16 + (lane & 15);
#pragma unroll
    for (int r = 0; r < 4; ++r) {
        const int d = (lane >> 4) * 4 + r;
        s[((size_t)u * 16 + d) * 64 + bcol] = ap[r];
    }
}

// ---- squash; writes out (b,u,d) and vTb bf16 [u][d][b] ----
__global__ __launch_bounds__(256) void v_kernel3(const float* __restrict__ s,
                                                 float* __restrict__ out,
                                                 unsigned short* __restrict__ vTb) {
    int n = blockIdx.x * 256 + threadIdx.x;     // grid = 4 -> 1024 = B*D
    int b = n >> 4, d = n & 15;
    float sv[32];
    float msq = 0.f;
#pragma unroll
    for (int u = 0; u < 32; ++u) {
        sv[u] = s[(u * 16 + d) * 64 + b];
        msq += sv[u] * sv[u];
    }
    float scale = msq / ((1.f + msq) * sqrtf(msq));
#pragma unroll
    for (int u = 0; u < 32; ++u) {
        float val = sv[u] * scale;
        out[(b * 32 + u) * 16 + d] = val;
        vTb[((size_t)u * 16 + d) * 64 + b] = (unsigned short)f2bf1(val);
    }
}

// ---- MFMA delta: delta[c,u] = (1/B) * sum_{d,i} W[c,u,d,i] * sum_b vT[u,d,b]*x2[c,i,b]
// GEMM tile: m=d(16), n=(c-pair,i)(16), k=b(64 -> 2 MFMAs). Epilogue dots acc with W tile.
// grid = 32 cg * 32 u ; block 256 = 4 waves ; wave: fixed u, 8 c-pairs.
template <int FIRST>
__global__ __launch_bounds__(256) void delta_mfma(const unsigned short* __restrict__ x2b,
                                                  const unsigned short* __restrict__ Wb,
                                                  const unsigned short* __restrict__ vTb,
                                                  float* __restrict__ bij) {
    const int cg = blockIdx.x >> 5;
    const int u  = blockIdx.x & 31;
    const int t = threadIdx.x, w = t >> 6, l = t & 63;
    const int m = l & 15, kb = l >> 4;
    const int ci = m & 7;          // i
    const int chalf = m >> 3;      // c parity within pair

    // A-frags (vT): row m=d, k=b
    const uint4 a0 = *reinterpret_cast<const uint4*>(vTb + ((size_t)u * 16 + m) * 64 + kb * 8);
    const uint4 a1 = *reinterpret_cast<const uint4*>(vTb + ((size_t)u * 16 + m) * 64 + 32 + kb * 8);

#pragma unroll 2
    for (int j = 0; j < 8; ++j) {
        const int cpair = cg * 32 + w * 8 + j;
        const int c = cpair * 2 + chalf;
        const uint4 b0 = *reinterpret_cast<const uint4*>(x2b + (size_t)c * 512 + ci * 64 + kb * 8);
        const uint4 b1 = *reinterpret_cast<const uint4*>(x2b + (size_t)c * 512 + ci * 64 + 32 + kb * 8);
        f32x4 acc = {0.f, 0.f, 0.f, 0.f};
        acc = __builtin_amdgcn_mfma_f32_16x16x32_bf16(
            __builtin_bit_cast(short8, a0), __builtin_bit_cast(short8, b0), acc, 0, 0, 0);
        acc = __builtin_amdgcn_mfma_f32_16x16x32_bf16(
            __builtin_bit_cast(short8, a1), __builtin_bit_cast(short8, b1), acc, 0, 0, 0);
        // epilogue: dot with W tile; D row d=(kb*4+r), col (chalf,ci)
        float dot = 0.f;
#pragma unroll
        for (int r = 0; r < 4; ++r) {
            const int d = kb * 4 + r;
            dot += acc[r] * bf1(Wb[((size_t)c * 32 + u) * 128 + d * 8 + ci]);
        }
        dot += __shfl_xor(dot, 16);
        dot += __shfl_xor(dot, 32);
        dot += __shfl_xor(dot, 1);
        dot += __shfl_xor(dot, 2);
        dot += __shfl_xor(dot, 4);
        if (l == 0 || l == 8) {
            const int cc = cpair * 2 + (l >> 3);
            float r = dot * (1.0f / 64.0f);
            if (!FIRST) r += bij[cc * 32 + u];
            bij[cc * 32 + u] = r;
        }
    }
}

extern "C" void kernel_launch(void* const* d_in, const int* in_sizes, int n_in,
                              void* d_out, int out_size, void* d_ws, size_t ws_size,
                              hipStream_t stream) {
    const float* x = (const float*)d_in[0];   // (B, I, C) = (64, 8, 2048)
    const float* W = (const float*)d_in[1];   // (C, U, D, I) = (2048, 32, 16, 8)
    float* out = (float*)d_out;

    float* ws   = (float*)d_ws;
    float* xt   = ws;                     // 1,048,576 f   [c][b][i] fp32
    float* part = xt + 1048576;           // 2,097,152 f
    float* bij  = part + 2097152;         // 65,536 f
    float* cij  = bij + 65536;            // 65,536 f
    float* s    = cij + 65536;            // 32,768 f
    unsigned short* Wb  = (unsigned short*)(s + 32768);   // 8,388,608 us
    unsigned short* x2b = Wb + 8388608;                   // 1,048,576 us  [c][i][b]
    unsigned short* vTb = x2b + 1048576;                  //    32,768 us  [u][d][b]

    transpose_kernel<<<256, 256, 0, stream>>>(x, xt, x2b);

    // it 0: uniform cij (bij = 0); smfma also emits Wb
    smfma_kernel<1, 1><<<2048, 256, 0, stream>>>(xt, W, Wb, cij, part);
    reduce_kernel<<<32, 256, 0, stream>>>(part, s);
    v_kernel3<<<4, 256, 0, stream>>>(s, out, vTb);
    delta_mfma<1><<<1024, 256, 0, stream>>>(x2b, Wb, vTb, bij);
    softmax_kernel<<<8, 256, 0, stream>>>(bij, cij);

    // it 1
    smfma_kernel<0, 2><<<2048, 256, 0, stream>>>(xt, W, Wb, cij, part);
    reduce_kernel<<<32, 256, 0, stream>>>(part, s);
    v_kernel3<<<4, 256, 0, stream>>>(s, out, vTb);
    delta_mfma<0><<<1024, 256, 0, stream>>>(x2b, Wb, vTb, bij);
    softmax_kernel<<<8, 256, 0, stream>>>(bij, cij);

    // it 2
    smfma_kernel<0, 2><<<2048, 256, 0, stream>>>(xt, W, Wb, cij, part);
    reduce_kernel<<<32, 256, 0, stream>>>(part, s);
    v_kernel3<<<4, 256, 0, stream>>>(s, out, vTb);
}

// Round 11
// 187.607 us; speedup vs baseline: 1.2676x; 1.0361x over previous
//
#include <hip/hip_runtime.h>

typedef __attribute__((ext_vector_type(8))) short short8;
typedef __attribute__((ext_vector_type(4))) float f32x4;

__device__ __forceinline__ unsigned int f2bf1(float f) {
    union { float f; unsigned int u; } v; v.f = f;
    return (v.u + 0x7fffu + ((v.u >> 16) & 1u)) >> 16;   // RNE
}
__device__ __forceinline__ unsigned int packbf(float a, float b) {
    return f2bf1(a) | (f2bf1(b) << 16);
}
__device__ __forceinline__ float bf1(unsigned short h) {
    union { unsigned int u; float f; } v; v.u = ((unsigned int)h) << 16;
    return v.f;
}
__device__ __forceinline__ unsigned int scale2(unsigned int p, float s) {
    float lo = bf1((unsigned short)(p & 0xffffu)) * s;
    float hi = bf1((unsigned short)(p >> 16)) * s;
    return packbf(lo, hi);
}

// ---- transpose: x (bi=512, c=2048) -> xbb[c][b][i] bf16  AND  x2b[c][i][b] bf16 ----
__global__ __launch_bounds__(256) void transpose_kernel(const float* __restrict__ x,
                                                        unsigned short* __restrict__ xbb,
                                                        unsigned short* __restrict__ x2b) {
    __shared__ float tile[64][65];
    const int bi0 = (blockIdx.x >> 5) << 6;
    const int c0  = (blockIdx.x & 31) << 6;
    const int tx = threadIdx.x & 63, ty = threadIdx.x >> 6;
#pragma unroll
    for (int p = 0; p < 16; ++p)
        tile[ty + p * 4][tx] = x[(size_t)(bi0 + ty + p * 4) * 2048 + c0 + tx];
    __syncthreads();
#pragma unroll
    for (int p = 0; p < 16; ++p) {
        const int c = c0 + ty + p * 4;
        const int bi = bi0 + tx;
        const unsigned short h = (unsigned short)f2bf1(tile[tx][ty + p * 4]);
        xbb[(size_t)c * 512 + bi] = h;                               // [c][b][i]
        x2b[(size_t)c * 512 + (bi & 7) * 64 + (bi >> 3)] = h;        // [c][i][b]
    }
}

// ---- fused softmax(bij) + W-scale: Wcb[c,u,d,i] = softmax_u(bij[c,:])[u] * Wb[c,u,d,i] ----
// grid = 2048 (1 c per block); block 256.
__global__ __launch_bounds__(256) void smws_kernel(const float* __restrict__ bij,
                                                   const unsigned short* __restrict__ Wb,
                                                   unsigned short* __restrict__ Wcb) {
    const int c = blockIdx.x;
    const int t = threadIdx.x;
    __shared__ float sm[32];
    if (t < 32) {
        float val = bij[c * 32 + t];
        float mx = val;
#pragma unroll
        for (int mask = 16; mask >= 1; mask >>= 1) mx = fmaxf(mx, __shfl_xor(mx, mask));
        float e = expf(val - mx);
        float ssum = e;
#pragma unroll
        for (int mask = 16; mask >= 1; mask >>= 1) ssum += __shfl_xor(ssum, mask);
        sm[t] = e / ssum;
    }
    __syncthreads();
#pragma unroll
    for (int j = 0; j < 2; ++j) {
        const int r = t * 2 + j;             // row (u,d): u = r>>4
        const float scale = sm[r >> 4];
        const size_t ofs = (size_t)c * 4096 + r * 8;
        uint4 h = *reinterpret_cast<const uint4*>(Wb + ofs);
        uint4 o;
        o.x = scale2(h.x, scale); o.y = scale2(h.y, scale);
        o.z = scale2(h.z, scale); o.w = scale2(h.w, scale);
        *reinterpret_cast<uint4*>(Wcb + ofs) = o;
    }
}

// ---- MFMA s-pass. MODE 1: read W fp32, pack, emit Wb, acc*(1/32). MODE 2: A = WA direct. ----
// grid = 64 chunks(32c) x 32 u ; lane: m = l&15 (d-row / b-col), kb = l>>4 (c-local)
template <int UNIFORM, int MODE>
__global__ __launch_bounds__(256) void smfma_kernel(const unsigned short* __restrict__ xbb,
                                                    const float* __restrict__ W,
                                                    unsigned short* __restrict__ Wb,
                                                    const unsigned short* __restrict__ WA,
                                                    float* __restrict__ part) {
    const int chunk = blockIdx.x >> 5;          // 0..63 (32 c each)
    const int u     = blockIdx.x & 31;
    const int t = threadIdx.x, w = t >> 6, l = t & 63;
    const int m  = l & 15;
    const int kb = l >> 4;
    const int b  = w * 16 + m;

    f32x4 acc0 = {0.f, 0.f, 0.f, 0.f}, acc1 = {0.f, 0.f, 0.f, 0.f};
    const int c00 = chunk * 32;

#pragma unroll
    for (int q = 0; q < 8; ++q) {
        const int c = c00 + q * 4 + kb;
        const size_t wofs = ((size_t)c * 32 + u) * 128 + m * 8;
        uint4 av;
        if (MODE == 1) {
            const float4* Wp = reinterpret_cast<const float4*>(W + wofs);
            float4 w0 = Wp[0], w1 = Wp[1];
            av.x = packbf(w0.x, w0.y); av.y = packbf(w0.z, w0.w);
            av.z = packbf(w1.x, w1.y); av.w = packbf(w1.z, w1.w);
            if (w == 0) *reinterpret_cast<uint4*>(Wb + wofs) = av;
        } else {
            av = *reinterpret_cast<const uint4*>(WA + wofs);
        }
        const uint4 bv = *reinterpret_cast<const uint4*>(xbb + ((size_t)c * 64 + b) * 8);
        if (q & 1)
            acc1 = __builtin_amdgcn_mfma_f32_16x16x32_bf16(
                __builtin_bit_cast(short8, av), __builtin_bit_cast(short8, bv), acc1, 0, 0, 0);
        else
            acc0 = __builtin_amdgcn_mfma_f32_16x16x32_bf16(
                __builtin_bit_cast(short8, av), __builtin_bit_cast(short8, bv), acc0, 0, 0, 0);
    }

    f32x4 acc = acc0 + acc1;
    if (UNIFORM) acc *= 0.03125f;
    *reinterpret_cast<f32x4*>(part + (size_t)blockIdx.x * 1024 + t * 4) = acc;
}

// ---- reduce over 64 chunks; emit s[u][d][b] ----
__global__ __launch_bounds__(256) void reduce_kernel(const float* __restrict__ part,
                                                     float* __restrict__ s) {
    const int tid = blockIdx.x * 256 + threadIdx.x;   // grid 32 -> 8192
    const int u = tid >> 8, w = (tid >> 6) & 3, lane = tid & 63;
    const float4* p = reinterpret_cast<const float4*>(part) + ((size_t)u * 256 + w * 64 + lane);
    float4 a = p[0];
#pragma unroll
    for (int k = 1; k < 64; ++k) {
        float4 q = p[(size_t)k * 8192];
        a.x += q.x; a.y += q.y; a.z += q.z; a.w += q.w;
    }
    const float* ap = &a.x;
    const int bcol = w * 16 + (lane & 15);
#pragma unroll
    for (int r = 0; r < 4; ++r) {
        const int d = (lane >> 4) * 4 + r;
        s[((size_t)u * 16 + d) * 64 + bcol] = ap[r];
    }
}

// ---- squash; writes out (b,u,d) fp32 and vTb bf16 [u][d][b] ----
__global__ __launch_bounds__(256) void v_kernel3(const float* __restrict__ s,
                                                 float* __restrict__ out,
                                                 unsigned short* __restrict__ vTb) {
    int n = blockIdx.x * 256 + threadIdx.x;     // grid = 4 -> 1024 = B*D
    int b = n >> 4, d = n & 15;
    float sv[32];
    float msq = 0.f;
#pragma unroll
    for (int u = 0; u < 32; ++u) {
        sv[u] = s[(u * 16 + d) * 64 + b];
        msq += sv[u] * sv[u];
    }
    float scale = msq / ((1.f + msq) * sqrtf(msq));
#pragma unroll
    for (int u = 0; u < 32; ++u) {
        float val = sv[u] * scale;
        out[(b * 32 + u) * 16 + d] = val;
        vTb[((size_t)u * 16 + d) * 64 + b] = (unsigned short)f2bf1(val);
    }
}

// ---- MFMA delta: delta[c,u] = (1/B) * sum_{d,i} W[c,u,d,i] * sum_b vT[u,d,b]*x2[c,i,b] ----
template <int FIRST>
__global__ __launch_bounds__(256) void delta_mfma(const unsigned short* __restrict__ x2b,
                                                  const unsigned short* __restrict__ Wb,
                                                  const unsigned short* __restrict__ vTb,
                                                  float* __restrict__ bij) {
    const int cg = blockIdx.x >> 5;
    const int u  = blockIdx.x & 31;
    const int t = threadIdx.x, w = t >> 6, l = t & 63;
    const int m = l & 15, kb = l >> 4;
    const int ci = m & 7;          // i
    const int chalf = m >> 3;      // c parity within pair

    const uint4 a0 = *reinterpret_cast<const uint4*>(vTb + ((size_t)u * 16 + m) * 64 + kb * 8);
    const uint4 a1 = *reinterpret_cast<const uint4*>(vTb + ((size_t)u * 16 + m) * 64 + 32 + kb * 8);

#pragma unroll 2
    for (int j = 0; j < 8; ++j) {
        const int cpair = cg * 32 + w * 8 + j;
        const int c = cpair * 2 + chalf;
        const uint4 b0 = *reinterpret_cast<const uint4*>(x2b + (size_t)c * 512 + ci * 64 + kb * 8);
        const uint4 b1 = *reinterpret_cast<const uint4*>(x2b + (size_t)c * 512 + ci * 64 + 32 + kb * 8);
        f32x4 acc = {0.f, 0.f, 0.f, 0.f};
        acc = __builtin_amdgcn_mfma_f32_16x16x32_bf16(
            __builtin_bit_cast(short8, a0), __builtin_bit_cast(short8, b0), acc, 0, 0, 0);
        acc = __builtin_amdgcn_mfma_f32_16x16x32_bf16(
            __builtin_bit_cast(short8, a1), __builtin_bit_cast(short8, b1), acc, 0, 0, 0);
        float dot = 0.f;
#pragma unroll
        for (int r = 0; r < 4; ++r) {
            const int d = kb * 4 + r;
            dot += acc[r] * bf1(Wb[((size_t)c * 32 + u) * 128 + d * 8 + ci]);
        }
        dot += __shfl_xor(dot, 16);
        dot += __shfl_xor(dot, 32);
        dot += __shfl_xor(dot, 1);
        dot += __shfl_xor(dot, 2);
        dot += __shfl_xor(dot, 4);
        if (l == 0 || l == 8) {
            const int cc = cpair * 2 + (l >> 3);
            float r = dot * (1.0f / 64.0f);
            if (!FIRST) r += bij[cc * 32 + u];
            bij[cc * 32 + u] = r;
        }
    }
}

extern "C" void kernel_launch(void* const* d_in, const int* in_sizes, int n_in,
                              void* d_out, int out_size, void* d_ws, size_t ws_size,
                              hipStream_t stream) {
    const float* x = (const float*)d_in[0];   // (B, I, C) = (64, 8, 2048)
    const float* W = (const float*)d_in[1];   // (C, U, D, I) = (2048, 32, 16, 8)
    float* out = (float*)d_out;

    float* ws   = (float*)d_ws;
    float* part = ws;                     // 2,097,152 f
    float* bij  = part + 2097152;         // 65,536 f
    float* s    = bij + 65536;            // 32,768 f
    unsigned short* Wb  = (unsigned short*)(s + 32768);   // 8,388,608 us
    unsigned short* Wcb = Wb + 8388608;                   // 8,388,608 us
    unsigned short* xbb = Wcb + 8388608;                  // 1,048,576 us  [c][b][i]
    unsigned short* x2b = xbb + 1048576;                  // 1,048,576 us  [c][i][b]
    unsigned short* vTb = x2b + 1048576;                  //    32,768 us  [u][d][b]

    transpose_kernel<<<256, 256, 0, stream>>>(x, xbb, x2b);

    // it 0: uniform cij = 1/32 folded into acc scale; smfma emits Wb
    smfma_kernel<1, 1><<<2048, 256, 0, stream>>>(xbb, W, Wb, Wb, part);
    reduce_kernel<<<32, 256, 0, stream>>>(part, s);
    v_kernel3<<<4, 256, 0, stream>>>(s, out, vTb);
    delta_mfma<1><<<1024, 256, 0, stream>>>(x2b, Wb, vTb, bij);

    // it 1
    smws_kernel<<<2048, 256, 0, stream>>>(bij, Wb, Wcb);
    smfma_kernel<0, 2><<<2048, 256, 0, stream>>>(xbb, W, Wb, Wcb, part);
    reduce_kernel<<<32, 256, 0, stream>>>(part, s);
    v_kernel3<<<4, 256, 0, stream>>>(s, out, vTb);
    delta_mfma<0><<<1024, 256, 0, stream>>>(x2b, Wb, vTb, bij);

    // it 2
    smws_kernel<<<2048, 256, 0, stream>>>(bij, Wb, Wcb);
    smfma_kernel<0, 2><<<2048, 256, 0, stream>>>(xbb, W, Wb, Wcb, part);
    reduce_kernel<<<32, 256, 0, stream>>>(part, s);
    v_kernel3<<<4, 256, 0, stream>>>(s, out, vTb);
}